// Round 3
// baseline (141.859 us; speedup 1.0000x reference)
//
#include <hip/hip_runtime.h>
#include <hip/hip_cooperative_groups.h>

namespace cg = cooperative_groups;

#define BB 2
#define NN 1024
#define FF 128
#define H1 64
#define H2 32

typedef __attribute__((ext_vector_type(8))) _Float16 half8;   // 8 f16 (4 VGPR)
typedef __attribute__((ext_vector_type(16))) float f32x16;    // 32x32 MFMA acc

// e = relu(a + b) in packed f16: 4x v_pk_add_f16 + 4x v_pk_max_f16
__device__ inline half8 addrelu8(half8 a, half8 b) {
    half8 s = a + b;
    const half8 z = {};
    return __builtin_elementwise_max(s, z);
}

// ---------------------------------------------------------------------------
// Fused single-launch kernel (cooperative): phase 1 = R2 precompute (blocks
// 0..511, 4 rows each, k-split waves), grid.sync(), phase 2 = R1/R2 edge body
// on all 1024 blocks. Removes one kernel launch + the drain/ramp gap between
// the two dispatches — the dominant residual per the R2 post-mortem
// (modeled device work ~6-7us vs 25.8us measured).
// __launch_bounds__(256,4): VGPR<=128 -> 4 blocks/CU -> exactly 1024
// co-resident blocks (cooperative launch validity by construction).
// ---------------------------------------------------------------------------
__global__ __launch_bounds__(256, 4) void fused_kernel(
    const float* __restrict__ x, const float* __restrict__ W1,
    const float* __restrict__ b1, const float* __restrict__ W2,
    const float* __restrict__ b2, const float* __restrict__ W3,
    const float* __restrict__ b3,
    _Float16* __restrict__ pj, _Float16* __restrict__ pib,
    _Float16* __restrict__ W2T, float* __restrict__ out)
{
    __shared__ float xs[4][FF];          // 2 KB   (phase 1)
    __shared__ float red[4][4][H1][2];   // 8 KB   (phase 1)
    __shared__ _Float16 plds[64][H1];    // 8 KB   (phase 2)

    const int tid  = threadIdx.x;
    const int lane = tid & 63;
    const int wv   = tid >> 6;

    // ================= phase 1: pj/pib precompute (blocks 0..511) =========
    if (blockIdx.x < 512) {
        const int h    = lane;
        const int row0 = blockIdx.x * 4;

        const float* xbase = x + (size_t)row0 * FF;
        for (int t = tid; t < 4 * FF; t += 256)
            xs[t >> 7][t & 127] = xbase[t];
        __syncthreads();

        float accj[4] = {}, acci[4] = {};
        const int k0 = wv * 32;
        #pragma unroll 8
        for (int kk = 0; kk < 32; ++kk) {
            const int k = k0 + kk;
            const float wj = W1[k * H1 + h];          // coalesced, once/block
            const float wi = W1[(FF + k) * H1 + h];
            #pragma unroll
            for (int r = 0; r < 4; ++r) {
                const float xv = xs[r][k];            // wave-uniform broadcast
                accj[r] = fmaf(xv, wj, accj[r]);
                acci[r] = fmaf(xv, wi, acci[r]);
            }
        }
        #pragma unroll
        for (int r = 0; r < 4; ++r) {
            red[wv][r][h][0] = accj[r];
            red[wv][r][h][1] = acci[r];
        }
        __syncthreads();

        #pragma unroll
        for (int half = 0; half < 2; ++half) {
            const int o = tid + half * 256;
            const int c = o & 1, hh = (o >> 1) & 63, r = o >> 7;
            const float s = red[0][r][hh][c] + red[1][r][hh][c]
                          + red[2][r][hh][c] + red[3][r][hh][c];
            const size_t idx = (size_t)(row0 + r) * H1 + hh;
            if (c == 0) pj[idx]  = (_Float16)s;
            else        pib[idx] = (_Float16)(s + b1[hh]);
        }

        if (blockIdx.x == 0) {   // fused W2 repack
            const int m = tid & 31, khi = tid >> 5;
            half8 v;
            #pragma unroll
            for (int e = 0; e < 8; ++e)
                v[e] = (_Float16)W2[(khi * 8 + e) * H2 + m];
            *(half8*)(W2T + (khi * 32 + m) * 8) = v;
        }
    }

    cg::this_grid().sync();   // device-scope visibility of pj/pib/W2T (G16)

    // ================= phase 2: edge kernel (all 1024 blocks) =============
    const int bid = blockIdx.x;
    const int b   = bid >> 9;                 // 512 blocks per batch
    const int rem = bid & 511;
    const int i0  = (rem >> 5) * 64;          // 16 i-tiles (64 rows each)
    const int j0  = (rem & 31) * 32;          // 32 j-tiles (32 cols each)
    const int jn  = lane & 31;                // m/n lane index
    const int hi  = lane >> 5;                // k-group half

    // ---- async stage: wave's 16 pib rows (2 KB) into LDS, linear dest ----
    {
        const _Float16* src = pib + (size_t)(b * NN + i0 + wv * 16) * H1 + lane * 8;
        char* dst = (char*)&plds[wv * 16][0];
        #pragma unroll
        for (int r = 0; r < 2; ++r)
            __builtin_amdgcn_global_load_lds(
                (const __attribute__((address_space(1))) void*)(src + r * 512),
                (__attribute__((address_space(3))) void*)(dst + r * 1024),
                16, 0, 0);
    }

    // A-frags: wa_c[e] = W2[16c + hi*8 + e][jn]  (4 b128 loads, fragment-ready)
    const half8 wa0 = *(const half8*)(W2T + ((0 + hi) * 32 + jn) * 8);
    const half8 wa1 = *(const half8*)(W2T + ((2 + hi) * 32 + jn) * 8);
    const half8 wa2 = *(const half8*)(W2T + ((4 + hi) * 32 + jn) * 8);
    const half8 wa3 = *(const half8*)(W2T + ((6 + hi) * 32 + jn) * 8);

    // B-frags (pj side), pinned: row j0+jn, k-slices 16c + hi*8
    const _Float16* pr = pj + (size_t)(b * NN + j0 + jn) * H1 + hi * 8;
    const half8 qj0 = *(const half8*)(pr);
    const half8 qj1 = *(const half8*)(pr + 16);
    const half8 qj2 = *(const half8*)(pr + 32);
    const half8 qj3 = *(const half8*)(pr + 48);

    f32x16 ci;
    float w3r[16];
    #pragma unroll
    for (int r = 0; r < 16; ++r) {           // D row mapping [m74/m101]
        const int row = (r & 3) + 8 * (r >> 2) + 4 * hi;
        ci[r]  = b2[row];
        w3r[r] = W3[row];
    }
    const float b3v = b3[0];

    __syncthreads();   // drains vmcnt (staging) then barrier

    const int srow = wv * 16;
    const _Float16* irbase = &plds[srow][0] + hi * 8;
    float* obase = out + (size_t)(b * NN + i0 + srow) * NN + j0 + jn;

    // prologue: load row 0 of this wave's 16
    half8 c0 = *(const half8*)(irbase);
    half8 c1 = *(const half8*)(irbase + 16);
    half8 c2 = *(const half8*)(irbase + 32);
    half8 c3 = *(const half8*)(irbase + 48);
    half8 n0, n1, n2, n3;
    float pe = 0.f;

    #pragma unroll 1
    for (int t = 0; t < 16; ++t) {
        if (t < 15) {                        // 1-row LDS lookahead
            const _Float16* ir = irbase + (t + 1) * H1;
            n0 = *(const half8*)(ir);
            n1 = *(const half8*)(ir + 16);
            n2 = *(const half8*)(ir + 32);
            n3 = *(const half8*)(ir + 48);
        }
        half8 e0 = addrelu8(qj0, c0);        // c* dies into e* (no reg growth)
        half8 e1 = addrelu8(qj1, c1);
        half8 e2 = addrelu8(qj2, c2);
        half8 e3 = addrelu8(qj3, c3);
        f32x16 d;
        d = __builtin_amdgcn_mfma_f32_32x32x16_f16(wa0, e0, ci, 0, 0, 0);
        d = __builtin_amdgcn_mfma_f32_32x32x16_f16(wa1, e1, d,  0, 0, 0);
        d = __builtin_amdgcn_mfma_f32_32x32x16_f16(wa2, e2, d,  0, 0, 0);
        d = __builtin_amdgcn_mfma_f32_32x32x16_f16(wa3, e3, d,  0, 0, 0);
        float p0 = 0.f, p1 = 0.f, p2 = 0.f, p3 = 0.f;   // 4 parallel chains
        #pragma unroll
        for (int r = 0; r < 4; ++r) {
            p0 = fmaf(fmaxf(d[r],      0.f), w3r[r],      p0);
            p1 = fmaf(fmaxf(d[4 + r],  0.f), w3r[4 + r],  p1);
            p2 = fmaf(fmaxf(d[8 + r],  0.f), w3r[8 + r],  p2);
            p3 = fmaf(fmaxf(d[12 + r], 0.f), w3r[12 + r], p3);
        }
        float p = (p0 + p1) + (p2 + p3);
        p += __shfl_xor(p, 32);              // lane-halves hold complementary rows
        if (t & 1) {                         // store a 2-row pair, full-wave
            float v = hi ? p : pe;           // hi half stores the odd row
            obase[(size_t)(t - 1 + hi) * NN] = v + b3v;
        } else {
            pe = p;
        }
        c0 = n0; c1 = n1; c2 = n2; c3 = n3;  // rotate pipeline regs
    }
}

// ---------------------------------------------------------------------------
// Fallback two-kernel path (R2, proven) — used only if cooperative launch
// is rejected at runtime.
// ---------------------------------------------------------------------------
__global__ __launch_bounds__(256) void precompute_kernel(
    const float* __restrict__ x, const float* __restrict__ W1,
    const float* __restrict__ b1, const float* __restrict__ W2,
    _Float16* __restrict__ pj, _Float16* __restrict__ pib,
    _Float16* __restrict__ W2T)
{
    __shared__ float xs[4][FF];
    __shared__ float red[4][4][H1][2];
    const int h  = threadIdx.x & 63;
    const int wv = threadIdx.x >> 6;
    const int row0 = blockIdx.x * 4;

    const float* xbase = x + (size_t)row0 * FF;
    for (int t = threadIdx.x; t < 4 * FF; t += 256)
        xs[t >> 7][t & 127] = xbase[t];
    __syncthreads();

    float accj[4] = {}, acci[4] = {};
    const int k0 = wv * 32;
    #pragma unroll 8
    for (int kk = 0; kk < 32; ++kk) {
        const int k = k0 + kk;
        const float wj = W1[k * H1 + h];
        const float wi = W1[(FF + k) * H1 + h];
        #pragma unroll
        for (int r = 0; r < 4; ++r) {
            const float xv = xs[r][k];
            accj[r] = fmaf(xv, wj, accj[r]);
            acci[r] = fmaf(xv, wi, acci[r]);
        }
    }
    #pragma unroll
    for (int r = 0; r < 4; ++r) {
        red[wv][r][h][0] = accj[r];
        red[wv][r][h][1] = acci[r];
    }
    __syncthreads();

    #pragma unroll
    for (int half = 0; half < 2; ++half) {
        const int o = threadIdx.x + half * 256;
        const int c = o & 1, hh = (o >> 1) & 63, r = o >> 7;
        const float s = red[0][r][hh][c] + red[1][r][hh][c]
                      + red[2][r][hh][c] + red[3][r][hh][c];
        const size_t idx = (size_t)(row0 + r) * H1 + hh;
        if (c == 0) pj[idx]  = (_Float16)s;
        else        pib[idx] = (_Float16)(s + b1[hh]);
    }

    if (blockIdx.x == 0) {
        const int m = threadIdx.x & 31, khi = threadIdx.x >> 5;
        half8 v;
        #pragma unroll
        for (int e = 0; e < 8; ++e)
            v[e] = (_Float16)W2[(khi * 8 + e) * H2 + m];
        *(half8*)(W2T + (khi * 32 + m) * 8) = v;
    }
}

__global__ __launch_bounds__(256, 4) void edge_kernel(
    const _Float16* __restrict__ pj, const _Float16* __restrict__ pib,
    const _Float16* __restrict__ W2T, const float* __restrict__ b2,
    const float* __restrict__ W3, const float* __restrict__ b3,
    float* __restrict__ out)
{
    __shared__ _Float16 plds[64][H1];

    const int lane = threadIdx.x & 63;
    const int wv   = threadIdx.x >> 6;
    const int b  = blockIdx.z;
    const int i0 = blockIdx.y * 64;
    const int j0 = blockIdx.x * 32;
    const int jn = lane & 31;
    const int hi = lane >> 5;

    {
        const _Float16* src = pib + (size_t)(b * NN + i0 + wv * 16) * H1 + lane * 8;
        char* dst = (char*)&plds[wv * 16][0];
        #pragma unroll
        for (int r = 0; r < 2; ++r)
            __builtin_amdgcn_global_load_lds(
                (const __attribute__((address_space(1))) void*)(src + r * 512),
                (__attribute__((address_space(3))) void*)(dst + r * 1024),
                16, 0, 0);
    }

    const half8 wa0 = *(const half8*)(W2T + ((0 + hi) * 32 + jn) * 8);
    const half8 wa1 = *(const half8*)(W2T + ((2 + hi) * 32 + jn) * 8);
    const half8 wa2 = *(const half8*)(W2T + ((4 + hi) * 32 + jn) * 8);
    const half8 wa3 = *(const half8*)(W2T + ((6 + hi) * 32 + jn) * 8);

    const _Float16* pr = pj + (size_t)(b * NN + j0 + jn) * H1 + hi * 8;
    const half8 qj0 = *(const half8*)(pr);
    const half8 qj1 = *(const half8*)(pr + 16);
    const half8 qj2 = *(const half8*)(pr + 32);
    const half8 qj3 = *(const half8*)(pr + 48);

    f32x16 ci;
    float w3r[16];
    #pragma unroll
    for (int r = 0; r < 16; ++r) {
        const int row = (r & 3) + 8 * (r >> 2) + 4 * hi;
        ci[r]  = b2[row];
        w3r[r] = W3[row];
    }
    const float b3v = b3[0];

    __syncthreads();

    const int srow = wv * 16;
    const _Float16* irbase = &plds[srow][0] + hi * 8;
    float* obase = out + (size_t)(b * NN + i0 + srow) * NN + j0 + jn;

    half8 c0 = *(const half8*)(irbase);
    half8 c1 = *(const half8*)(irbase + 16);
    half8 c2 = *(const half8*)(irbase + 32);
    half8 c3 = *(const half8*)(irbase + 48);
    half8 n0, n1, n2, n3;
    float pe = 0.f;

    #pragma unroll 1
    for (int t = 0; t < 16; ++t) {
        if (t < 15) {
            const _Float16* ir = irbase + (t + 1) * H1;
            n0 = *(const half8*)(ir);
            n1 = *(const half8*)(ir + 16);
            n2 = *(const half8*)(ir + 32);
            n3 = *(const half8*)(ir + 48);
        }
        half8 e0 = addrelu8(qj0, c0);
        half8 e1 = addrelu8(qj1, c1);
        half8 e2 = addrelu8(qj2, c2);
        half8 e3 = addrelu8(qj3, c3);
        f32x16 d;
        d = __builtin_amdgcn_mfma_f32_32x32x16_f16(wa0, e0, ci, 0, 0, 0);
        d = __builtin_amdgcn_mfma_f32_32x32x16_f16(wa1, e1, d,  0, 0, 0);
        d = __builtin_amdgcn_mfma_f32_32x32x16_f16(wa2, e2, d,  0, 0, 0);
        d = __builtin_amdgcn_mfma_f32_32x32x16_f16(wa3, e3, d,  0, 0, 0);
        float p0 = 0.f, p1 = 0.f, p2 = 0.f, p3 = 0.f;
        #pragma unroll
        for (int r = 0; r < 4; ++r) {
            p0 = fmaf(fmaxf(d[r],      0.f), w3r[r],      p0);
            p1 = fmaf(fmaxf(d[4 + r],  0.f), w3r[4 + r],  p1);
            p2 = fmaf(fmaxf(d[8 + r],  0.f), w3r[8 + r],  p2);
            p3 = fmaf(fmaxf(d[12 + r], 0.f), w3r[12 + r], p3);
        }
        float p = (p0 + p1) + (p2 + p3);
        p += __shfl_xor(p, 32);
        if (t & 1) {
            float v = hi ? p : pe;
            obase[(size_t)(t - 1 + hi) * NN] = v + b3v;
        } else {
            pe = p;
        }
        c0 = n0; c1 = n1; c2 = n2; c3 = n3;
    }
}

extern "C" void kernel_launch(void* const* d_in, const int* in_sizes, int n_in,
                              void* d_out, int out_size, void* d_ws, size_t ws_size,
                              hipStream_t stream) {
    const float* x  = (const float*)d_in[0];
    // d_in[1] = adj (UNUSED by reference), d_in[2] = mask (UNUSED)
    const float* W1 = (const float*)d_in[3];
    const float* b1 = (const float*)d_in[4];
    const float* W2 = (const float*)d_in[5];
    const float* b2 = (const float*)d_in[6];
    const float* W3 = (const float*)d_in[7];
    const float* b3 = (const float*)d_in[8];
    float* out = (float*)d_out;

    _Float16* pj  = (_Float16*)d_ws;                    // B*N*H1 f16 = 256 KB
    _Float16* pib = pj + (size_t)BB * NN * H1;          // B*N*H1 f16 = 256 KB
    _Float16* W2T = pib + (size_t)BB * NN * H1;         // 64*32 f16 = 4 KB

    void* args[] = {(void*)&x, (void*)&W1, (void*)&b1, (void*)&W2, (void*)&b2,
                    (void*)&W3, (void*)&b3, (void*)&pj, (void*)&pib,
                    (void*)&W2T, (void*)&out};
    hipError_t err = hipLaunchCooperativeKernel(
        (const void*)fused_kernel, dim3(BB * NN / 2), dim3(256), args, 0, stream);

    if (err != hipSuccess) {   // fallback: proven two-kernel path (R2)
        precompute_kernel<<<BB * NN / 4, 256, 0, stream>>>(x, W1, b1, W2, pj, pib, W2T);
        edge_kernel<<<dim3(NN / 32, NN / 64, BB), 256, 0, stream>>>(
            pj, pib, W2T, b2, W3, b3, out);
    }
}

// Round 4
// 52.914 us; speedup vs baseline: 2.6810x; 2.6810x over previous
//
#include <hip/hip_runtime.h>

#define BB 2
#define NN 1024
#define FF 128
#define H1 64
#define H2 32
#define MAGIC 0x5F3E2A19u

typedef __attribute__((ext_vector_type(8))) _Float16 half8;   // 8 f16 (4 VGPR)
typedef __attribute__((ext_vector_type(16))) float f32x16;    // 32x32 MFMA acc

// e = relu(a + b) in packed f16: 4x v_pk_add_f16 + 4x v_pk_max_f16
__device__ inline half8 addrelu8(half8 a, half8 b) {
    half8 s = a + b;
    const half8 z = {};
    return __builtin_elementwise_max(s, z);
}

// ---------------------------------------------------------------------------
// Single-launch fused kernel, NO grid barrier (R3 showed cg::grid().sync()
// costs ~115us on 1024 blocks). Producer->consumer handshake instead:
//   blocks 0..511 run the R2 precompute (4 rows each), then device-release
//   a per-row-block flag. Every block, before its edge phase, polls ONLY the
//   24 flags it depends on (16 i-row-blocks + 8 j-row-blocks) and proceeds.
// No global rendezvous; edge tiles start as soon as their producers finish.
// Deadlock-free by construction: __launch_bounds__(256,4) (VGPR<=128) and
// 10.25KB LDS make all 1024 blocks co-resident, so producers always run.
// W2T removed: A-fragments are loaded straight from W2 (32 coalesced f32
// per lane, L2-resident) — drops the block-0 special case and its flag.
// ---------------------------------------------------------------------------
__global__ __launch_bounds__(256, 4) void fused_kernel(
    const float* __restrict__ x, const float* __restrict__ W1,
    const float* __restrict__ b1, const float* __restrict__ W2,
    const float* __restrict__ b2, const float* __restrict__ W3,
    const float* __restrict__ b3,
    _Float16* __restrict__ pj, _Float16* __restrict__ pib,
    unsigned int* __restrict__ flags, float* __restrict__ out)
{
    // phase-1 view: xs[4][128] (2KB) + red[4][4][64][2] (8KB) = 10.25KB
    // phase-2 view: plds[64][64] f16 (8KB) — overlaid, separated by barrier
    __shared__ __align__(16) char smem[10240];
    float (*xs)[FF]          = (float(*)[FF])smem;
    float (*red)[4][H1][2]   = (float(*)[4][H1][2])(smem + 2048);
    _Float16 (*plds)[H1]     = (_Float16(*)[H1])smem;

    const int tid  = threadIdx.x;
    const int lane = tid & 63;
    const int wv   = tid >> 6;
    const int bid  = blockIdx.x;

    // ============ phase 1: pj/pib precompute (blocks 0..511) ==============
    if (bid < 512) {
        const int h    = lane;
        const int row0 = bid * 4;                 // global row (b*NN folded in)

        const float* xbase = x + (size_t)row0 * FF;
        for (int t = tid; t < 4 * FF; t += 256)
            xs[t >> 7][t & 127] = xbase[t];
        __syncthreads();

        float accj[4] = {}, acci[4] = {};
        const int k0 = wv * 32;
        #pragma unroll 8
        for (int kk = 0; kk < 32; ++kk) {
            const int k = k0 + kk;
            const float wj = W1[k * H1 + h];          // coalesced, once/block
            const float wi = W1[(FF + k) * H1 + h];
            #pragma unroll
            for (int r = 0; r < 4; ++r) {
                const float xv = xs[r][k];            // wave-uniform broadcast
                accj[r] = fmaf(xv, wj, accj[r]);
                acci[r] = fmaf(xv, wi, acci[r]);
            }
        }
        #pragma unroll
        for (int r = 0; r < 4; ++r) {
            red[wv][r][h][0] = accj[r];
            red[wv][r][h][1] = acci[r];
        }
        __syncthreads();

        #pragma unroll
        for (int half = 0; half < 2; ++half) {
            const int o = tid + half * 256;
            const int c = o & 1, hh = (o >> 1) & 63, r = o >> 7;
            const float s = red[0][r][hh][c] + red[1][r][hh][c]
                          + red[2][r][hh][c] + red[3][r][hh][c];
            const size_t idx = (size_t)(row0 + r) * H1 + hh;
            if (c == 0) pj[idx]  = (_Float16)s;
            else        pib[idx] = (_Float16)(s + b1[hh]);
        }

        // publish: stores drained to L2 by the barrier in the poll below is
        // NOT enough (other blocks read) -> explicit device-scope release.
        __syncthreads();                      // all waves' stores at vmcnt(0)
        if (tid == 0) {
            __threadfence();                  // agent-scope writeback
            __hip_atomic_store(&flags[bid], MAGIC,
                               __ATOMIC_RELEASE, __HIP_MEMORY_SCOPE_AGENT);
        }
    }

    // ============ phase 2: edge tile (all 1024 blocks) ====================
    const int b   = bid >> 9;                 // 512 blocks per batch
    const int rem = bid & 511;
    const int i0  = (rem >> 5) * 64;          // 16 i-tiles (64 rows each)
    const int j0  = (rem & 31) * 32;          // 32 j-tiles (32 cols each)
    const int jn  = lane & 31;                // m/n lane index
    const int hi  = lane >> 5;                // k-group half

    // wait for the 24 producer row-blocks this tile reads (i:16, j:8)
    {
        const int fi0 = (b * NN + i0) >> 2;
        const int fj0 = (b * NN + j0) >> 2;
        if (tid < 24) {
            const int f = tid < 16 ? fi0 + tid : fj0 + (tid - 16);
            while (__hip_atomic_load(&flags[f], __ATOMIC_ACQUIRE,
                                     __HIP_MEMORY_SCOPE_AGENT) != MAGIC)
                __builtin_amdgcn_s_sleep(4);
        }
        __syncthreads();   // also separates phase-1 LDS use from plds reuse
    }

    // ---- async stage: wave's 16 pib rows (2 KB) into LDS, linear dest ----
    {
        const _Float16* src = pib + (size_t)(b * NN + i0 + wv * 16) * H1 + lane * 8;
        char* dst = (char*)&plds[wv * 16][0];
        #pragma unroll
        for (int r = 0; r < 2; ++r)
            __builtin_amdgcn_global_load_lds(
                (const __attribute__((address_space(1))) void*)(src + r * 512),
                (__attribute__((address_space(3))) void*)(dst + r * 1024),
                16, 0, 0);
    }

    // A-frags straight from W2 (L2-resident, coalesced along jn):
    //   wa[c][e] = (f16)W2[16c + hi*8 + e][jn]
    half8 wa[4];
    #pragma unroll
    for (int c4 = 0; c4 < 4; ++c4)
        #pragma unroll
        for (int e = 0; e < 8; ++e)
            wa[c4][e] = (_Float16)W2[(16 * c4 + hi * 8 + e) * H2 + jn];

    // B-frags (pj side), pinned: row j0+jn, k-slices 16c + hi*8
    const _Float16* pr = pj + (size_t)(b * NN + j0 + jn) * H1 + hi * 8;
    const half8 qj0 = *(const half8*)(pr);
    const half8 qj1 = *(const half8*)(pr + 16);
    const half8 qj2 = *(const half8*)(pr + 32);
    const half8 qj3 = *(const half8*)(pr + 48);

    f32x16 ci;
    float w3r[16];
    #pragma unroll
    for (int r = 0; r < 16; ++r) {           // D row mapping [m74/m101]
        const int row = (r & 3) + 8 * (r >> 2) + 4 * hi;
        ci[r]  = b2[row];
        w3r[r] = W3[row];
    }
    const float b3v = b3[0];

    __syncthreads();   // drains vmcnt (staging) then barrier

    const int srow = wv * 16;
    const _Float16* irbase = &plds[srow][0] + hi * 8;
    float* obase = out + (size_t)(b * NN + i0 + srow) * NN + j0 + jn;

    // prologue: load row 0 of this wave's 16
    half8 c0 = *(const half8*)(irbase);
    half8 c1 = *(const half8*)(irbase + 16);
    half8 c2 = *(const half8*)(irbase + 32);
    half8 c3 = *(const half8*)(irbase + 48);
    half8 n0, n1, n2, n3;
    float pe = 0.f;

    #pragma unroll 1
    for (int t = 0; t < 16; ++t) {
        if (t < 15) {                        // 1-row LDS lookahead
            const _Float16* ir = irbase + (t + 1) * H1;
            n0 = *(const half8*)(ir);
            n1 = *(const half8*)(ir + 16);
            n2 = *(const half8*)(ir + 32);
            n3 = *(const half8*)(ir + 48);
        }
        half8 e0 = addrelu8(qj0, c0);        // c* dies into e* (no reg growth)
        half8 e1 = addrelu8(qj1, c1);
        half8 e2 = addrelu8(qj2, c2);
        half8 e3 = addrelu8(qj3, c3);
        f32x16 d;
        d = __builtin_amdgcn_mfma_f32_32x32x16_f16(wa[0], e0, ci, 0, 0, 0);
        d = __builtin_amdgcn_mfma_f32_32x32x16_f16(wa[1], e1, d,  0, 0, 0);
        d = __builtin_amdgcn_mfma_f32_32x32x16_f16(wa[2], e2, d,  0, 0, 0);
        d = __builtin_amdgcn_mfma_f32_32x32x16_f16(wa[3], e3, d,  0, 0, 0);
        float p0 = 0.f, p1 = 0.f, p2 = 0.f, p3 = 0.f;   // 4 parallel chains
        #pragma unroll
        for (int r = 0; r < 4; ++r) {
            p0 = fmaf(fmaxf(d[r],      0.f), w3r[r],      p0);
            p1 = fmaf(fmaxf(d[4 + r],  0.f), w3r[4 + r],  p1);
            p2 = fmaf(fmaxf(d[8 + r],  0.f), w3r[8 + r],  p2);
            p3 = fmaf(fmaxf(d[12 + r], 0.f), w3r[12 + r], p3);
        }
        float p = (p0 + p1) + (p2 + p3);
        p += __shfl_xor(p, 32);              // lane-halves hold complementary rows
        if (t & 1) {                         // store a 2-row pair, full-wave
            float v = hi ? p : pe;           // hi half stores the odd row
            obase[(size_t)(t - 1 + hi) * NN] = v + b3v;
        } else {
            pe = p;
        }
        c0 = n0; c1 = n1; c2 = n2; c3 = n3;  // rotate pipeline regs
    }
}

extern "C" void kernel_launch(void* const* d_in, const int* in_sizes, int n_in,
                              void* d_out, int out_size, void* d_ws, size_t ws_size,
                              hipStream_t stream) {
    const float* x  = (const float*)d_in[0];
    // d_in[1] = adj (UNUSED by reference), d_in[2] = mask (UNUSED)
    const float* W1 = (const float*)d_in[3];
    const float* b1 = (const float*)d_in[4];
    const float* W2 = (const float*)d_in[5];
    const float* b2 = (const float*)d_in[6];
    const float* W3 = (const float*)d_in[7];
    const float* b3 = (const float*)d_in[8];
    float* out = (float*)d_out;

    _Float16* pj  = (_Float16*)d_ws;                    // B*N*H1 f16 = 256 KB
    _Float16* pib = pj + (size_t)BB * NN * H1;          // B*N*H1 f16 = 256 KB
    unsigned int* flags = (unsigned int*)(pib + (size_t)BB * NN * H1); // 2 KB

    fused_kernel<<<BB * NN / 2, 256, 0, stream>>>(
        x, W1, b1, W2, b2, W3, b3, pj, pib, flags, out);
}